// Round 14
// baseline (387.454 us; speedup 1.0000x reference)
//
#include <hip/hip_runtime.h>
#include <math.h>

#define NN    16384
#define EE    262144
#define ET    (EE + NN)      // edges + self loops
#define NB    8
#define IN_F  768
#define HID1  256
#define H1    4
#define D1    (H1*HID1)      // 1024
#define OUT2  128
#define H2    2
#define D2    (H2*OUT2)      // 256

typedef __attribute__((ext_vector_type(8))) _Float16 f16x8;
typedef __attribute__((ext_vector_type(4))) float f32x4;

__device__ __forceinline__ float hf2f(unsigned short u) {
    union { unsigned short u; _Float16 h; } c; c.u = u; return (float)c.h;
}
__device__ __forceinline__ unsigned short f2hf(float f) {
    union { unsigned short u; _Float16 h; } c; c.h = (_Float16)f; return c.u;
}

// ---------------- device-scope grid barrier (co-resident grids only) ----------------

__device__ __forceinline__ void grid_barrier(int* cnt, int* gen, int nb) {
    __syncthreads();
    if (threadIdx.x == 0) {
        int g = __hip_atomic_load(gen, __ATOMIC_RELAXED, __HIP_MEMORY_SCOPE_AGENT);
        int v = __hip_atomic_fetch_add(cnt, 1, __ATOMIC_ACQ_REL, __HIP_MEMORY_SCOPE_AGENT);
        if (v == nb - 1) {
            __hip_atomic_store(cnt, 0, __ATOMIC_RELAXED, __HIP_MEMORY_SCOPE_AGENT);
            __hip_atomic_fetch_add(gen, 1, __ATOMIC_RELEASE, __HIP_MEMORY_SCOPE_AGENT);
        } else {
            while (__hip_atomic_load(gen, __ATOMIC_ACQUIRE, __HIP_MEMORY_SCOPE_AGENT) == g)
                __builtin_amdgcn_s_sleep(2);
        }
    }
    __syncthreads();
}

// ---------------- prep: fp32->fp16 conversions + workspace zero-fill ----------------

__global__ void prep_kernel(const float* __restrict__ x,  unsigned short* __restrict__ xo,
                            const float* __restrict__ w1, unsigned short* __restrict__ w1o,
                            const float* __restrict__ w2, unsigned short* __restrict__ w2o,
                            float4* __restrict__ zbase, int zunits) {
    const int n1 = NN * IN_F / 4;
    const int n2 = D1 * IN_F / 4;
    const int n3 = D2 * D1 / 4;
    int i = blockIdx.x * blockDim.x + threadIdx.x;
    if (i < n1 + n2 + n3) {
        const float* src; unsigned short* dst; int j;
        if (i < n1)           { src = x;  dst = xo;  j = i; }
        else if (i < n1 + n2) { src = w1; dst = w1o; j = i - n1; }
        else                  { src = w2; dst = w2o; j = i - n1 - n2; }
        float4 v = ((const float4*)src)[j];
        ushort4 h;
        h.x = f2hf(v.x); h.y = f2hf(v.y); h.z = f2hf(v.z); h.w = f2hf(v.w);
        ((ushort4*)dst)[j] = h;
    } else {
        int j = i - (n1 + n2 + n3);
        if (j < zunits) zbase[j] = make_float4(0.f, 0.f, 0.f, 0.f);
    }
}

// ---------------- CSR build (proven r10 versions) ----------------

__global__ void hist_kernel(const int* __restrict__ ei, const int* __restrict__ batch,
                            int* __restrict__ deg, int* __restrict__ n_g, int* __restrict__ e_cnt) {
    __shared__ int le[NB], ln[NB];
    int tid = threadIdx.x;
    if (tid < NB) { le[tid] = 0; ln[tid] = 0; }
    __syncthreads();
    int t = blockIdx.x * blockDim.x + tid;
    if (t < EE) {
        int s = ei[t];
        int d = ei[EE + t];
        atomicAdd(&deg[d], 1);
        atomicAdd(&le[batch[s]], 1);
    }
    if (t < NN) {
        atomicAdd(&ln[batch[t]], 1);
    }
    __syncthreads();
    if (tid < NB) {
        if (le[tid]) atomicAdd(&e_cnt[tid], le[tid]);
        if (ln[tid]) atomicAdd(&n_g[tid], ln[tid]);
    }
}

__global__ __launch_bounds__(1024) void scan_kernel(const int* __restrict__ deg, int* __restrict__ row_ptr) {
    __shared__ int sums[1024];
    int t = threadIdx.x;
    int base = t * 16;
    int local[16];
    int acc = 0;
#pragma unroll
    for (int i = 0; i < 16; i++) { local[i] = acc; acc += deg[base + i] + 1; }  // +1 = self loop
    sums[t] = acc;
    __syncthreads();
    for (int off = 1; off < 1024; off <<= 1) {
        int v = (t >= off) ? sums[t - off] : 0;
        __syncthreads();
        sums[t] += v;
        __syncthreads();
    }
    int prev = (t == 0) ? 0 : sums[t - 1];
#pragma unroll
    for (int i = 0; i < 16; i++) row_ptr[base + i] = prev + local[i];
    if (t == 1023) row_ptr[NN] = sums[1023];
}

// ---------------- fp16 MFMA GEMM (+ optional scatter trailing blocks) ----------------

__device__ __forceinline__ void ld_lds16(const unsigned short* g, unsigned short* l) {
    __builtin_amdgcn_global_load_lds((__attribute__((address_space(1))) void*)g,
                                     (__attribute__((address_space(3))) void*)l, 16, 0, 0);
}

#define BM 128
#define BN 128
#define BK 32

__global__ __launch_bounds__(256) void gemm_mfma(const unsigned short* __restrict__ A,
                                                 const unsigned short* __restrict__ B,
                                                 unsigned short* __restrict__ C,
                                                 int M, int N, int K,
                                                 int gemmBlocks,
                                                 const int* __restrict__ ei,
                                                 const int* __restrict__ row_ptr,
                                                 int* __restrict__ cursor,
                                                 int* __restrict__ colidx) {
    if ((int)blockIdx.x >= gemmBlocks) {
        int t = (blockIdx.x - gemmBlocks) * 256 + threadIdx.x;
        if (t < ET) {
            int s, d;
            if (t < EE) { s = ei[t]; d = ei[EE + t]; }
            else        { s = d = t - EE; }
            int pos = row_ptr[d] + atomicAdd(&cursor[d], 1);
            colidx[pos] = s;
        }
        return;
    }

    __shared__ __align__(16) unsigned short sA[BM * BK];
    __shared__ __align__(16) unsigned short sB[BN * BK];
    int t = threadIdx.x;
    int lane = t & 63, wave = t >> 6;

    // XCD swizzle: row-stripe r = (b/8/NC)*8 + b%8, col c = (b/8)%NC
    int NC = N / BN;
    int b = blockIdx.x;
    int xcd = b & 7;
    int idx = b >> 3;
    int c = idx % NC;
    int rg = idx / NC;
    int bm = (rg * 8 + xcd) * BM;
    int bn = c * BN;

    int wm = (wave & 1) * 64, wn = (wave >> 1) * 64;

    // staging: wave0/1 -> A rows 0-63 / 64-127; wave2/3 -> B halves
    const unsigned short* gbase;
    unsigned short* lbase;
    {
        int hrow = (wave & 1) * 64;
        if (wave < 2) { gbase = A + (size_t)(bm + hrow) * K; lbase = sA + hrow * BK; }
        else          { gbase = B + (size_t)(bn + hrow) * K; lbase = sB + hrow * BK; }
    }
    int schunk = (lane & 3) ^ ((lane >> 3) & 3);
    const unsigned short* gsrc = gbase + (size_t)(lane >> 2) * K + schunk * 8;

    f32x4 zero = {0.f, 0.f, 0.f, 0.f};
    f32x4 acc[4][4];
#pragma unroll
    for (int i = 0; i < 4; i++)
#pragma unroll
        for (int j = 0; j < 4; j++) acc[i][j] = zero;

    int row16 = lane & 15;
    int kq = ((lane >> 4) ^ ((row16 >> 1) & 3)) * 8;

    for (int k0 = 0; k0 < K; k0 += BK) {
#pragma unroll
        for (int i = 0; i < 4; i++)
            ld_lds16(gsrc + k0 + (size_t)(i * 16) * K, lbase + i * 16 * BK);
        __syncthreads();

        f16x8 ah[4], bh[4];
#pragma unroll
        for (int mt = 0; mt < 4; mt++)
            ah[mt] = *(const f16x8*)&sA[(wm + mt * 16 + row16) * BK + kq];
#pragma unroll
        for (int nt = 0; nt < 4; nt++)
            bh[nt] = *(const f16x8*)&sB[(wn + nt * 16 + row16) * BK + kq];
#pragma unroll
        for (int mt = 0; mt < 4; mt++)
#pragma unroll
            for (int nt = 0; nt < 4; nt++)
                acc[mt][nt] = __builtin_amdgcn_mfma_f32_16x16x32_f16(ah[mt], bh[nt], acc[mt][nt], 0, 0, 0);
        __syncthreads();
    }

    int crow0 = bm + wm + (lane >> 4) * 4;
    int ccol0 = bn + wn + row16;
#pragma unroll
    for (int mt = 0; mt < 4; mt++)
#pragma unroll
        for (int nt = 0; nt < 4; nt++)
#pragma unroll
            for (int reg = 0; reg < 4; reg++)
                C[(size_t)(crow0 + mt * 16 + reg) * N + ccol0 + nt * 16] = f2hf(acc[mt][nt][reg]);
}

// ---------------- attention logits: one wave per (node, head), vector loads ----------------

__global__ __launch_bounds__(256) void al1_kernel(const unsigned short* __restrict__ h,
                                                  const float* __restrict__ a_s,
                                                  const float* __restrict__ a_d,
                                                  float* __restrict__ als,
                                                  float* __restrict__ ald) {
    int node = blockIdx.x;
    int head = threadIdx.x >> 6;
    int lane = threadIdx.x & 63;
    int co = head * HID1 + lane * 4;
    ushort4 hv = *(const ushort4*)(h + (size_t)node * D1 + co);
    float4 as = *(const float4*)(a_s + co);
    float4 ad = *(const float4*)(a_d + co);
    float h0 = hf2f(hv.x), h1 = hf2f(hv.y), h2 = hf2f(hv.z), h3 = hf2f(hv.w);
    float ss = h0 * as.x + h1 * as.y + h2 * as.z + h3 * as.w;
    float sd = h0 * ad.x + h1 * ad.y + h2 * ad.z + h3 * ad.w;
#pragma unroll
    for (int off = 32; off; off >>= 1) {
        ss += __shfl_down(ss, off);
        sd += __shfl_down(sd, off);
    }
    if (lane == 0) {
        als[node * H1 + head] = ss;
        ald[node * H1 + head] = sd;
    }
}

__global__ __launch_bounds__(256) void al2_kernel(const unsigned short* __restrict__ h,
                                                  const float* __restrict__ a_s,
                                                  const float* __restrict__ a_d,
                                                  float* __restrict__ als,
                                                  float* __restrict__ ald) {
    int unit = threadIdx.x >> 6;            // 4 units: 2 nodes x 2 heads
    int node = blockIdx.x * 2 + (unit >> 1);
    int head = unit & 1;
    int lane = threadIdx.x & 63;
    int co = head * OUT2 + lane * 2;
    ushort2 hv = *(const ushort2*)(h + (size_t)node * D2 + co);
    float2 as = *(const float2*)(a_s + co);
    float2 ad = *(const float2*)(a_d + co);
    float h0 = hf2f(hv.x), h1 = hf2f(hv.y);
    float ss = h0 * as.x + h1 * as.y;
    float sd = h0 * ad.x + h1 * ad.y;
#pragma unroll
    for (int off = 32; off; off >>= 1) {
        ss += __shfl_down(ss, off);
        sd += __shfl_down(sd, off);
    }
    if (lane == 0) {
        als[node * H2 + head] = ss;
        ald[node * H2 + head] = sd;
    }
}

__device__ __forceinline__ float leaky(float v) { return v > 0.f ? v : 0.2f * v; }
__device__ __forceinline__ float elu1(float v) { return v > 0.f ? v : (__expf(v) - 1.f); }

// ---------------- GAT layer 1 aggregation: channel-sliced + 2-dst half-waves ----------------
// Now L2-resident (FETCH 51 MB) and latency-bound (BW 1.3 TB/s, VALU 55%):
// 2-deep double-buffered gather pipeline -- group g+1's 8 loads issue BEFORE
// group g's FMAs. Slot index clamped to 31 (phantom slots carry w=0), so the
// accumulate sequence is bit-identical. (r3's null for this technique was in
// the pre-slicing fabric-BW-bound regime; mechanism applies here, not there.)

__global__ __launch_bounds__(256) void agg1_kernel(const unsigned short* __restrict__ h,
                                                   const float* __restrict__ als,
                                                   const float* __restrict__ ald,
                                                   const int* __restrict__ row_ptr,
                                                   const int* __restrict__ colidx,
                                                   const float* __restrict__ bias,
                                                   unsigned short* __restrict__ outp) {
    int b = blockIdx.x;
    int s = b & 7;             // slice -> XCD s
    int g = b >> 3;            // group of 8 dsts
    int wave = threadIdx.x >> 6;
    int lane = threadIdx.x & 63;
    int lanesel = lane & 32;   // half select
    int l5 = lane & 31;
    int d = g * 8 + wave * 2 + (lanesel >> 5);
    int head = s >> 1;
    int start = row_ptr[d], end = row_ptr[d + 1];
    int deg = end - start;
    int degO = __shfl_xor(deg, 32);
    int degmax = max(deg, degO);
    float ald_h = ald[d * H1 + head];
    unsigned choff = (unsigned)(s * 128 + l5 * 4);   // shorts within row

    float a0 = 0.f, a1 = 0.f, a2 = 0.f, a3 = 0.f;
    float wsum = 0.f;

    for (int c0 = 0; c0 < degmax; c0 += 32) {
        int ee = start + c0 + l5;
        int idx = ee < end ? ee : end - 1;
        int sL = colidx[idx];
        float ev = leaky(als[(sL << 2) + head] + ald_h);
        float wL = (ee < end) ? __expf(ev) : 0.f;
        float ws = wL;
        ws += __shfl_xor(ws, 16); ws += __shfl_xor(ws, 8);
        ws += __shfl_xor(ws, 4);  ws += __shfl_xor(ws, 2);  ws += __shfl_xor(ws, 1);
        wsum += ws;

        int n = degmax - c0; if (n > 32) n = 32;
        int ngr = ((n + 7) & ~7) >> 3;   // 8-edge groups (1..4)

        ushort4 hvA[8], hvB[8];
        float wvA[8], wvB[8];

#define AG1_ISS(WV, HV, BASE)                                                    \
        {                                                                        \
            _Pragma("unroll")                                                    \
            for (int j = 0; j < 8; j++) {                                        \
                int kk = (BASE) + j; kk = kk < 32 ? kk : 31;                     \
                int src = kk + lanesel;                                          \
                int ssj = __shfl(sL, src);                                       \
                WV[j]   = __shfl(wL, src);                                       \
                HV[j] = *(const ushort4*)(h + (((unsigned)ssj << 10) + choff));  \
            }                                                                    \
        }
#define AG1_FMA(WV, HV)                                                          \
        {                                                                        \
            _Pragma("unroll")                                                    \
            for (int j = 0; j < 8; j++) {                                        \
                float w = WV[j];                                                 \
                a0 += w * hf2f(HV[j].x); a1 += w * hf2f(HV[j].y);                \
                a2 += w * hf2f(HV[j].z); a3 += w * hf2f(HV[j].w);                \
            }                                                                    \
        }

        AG1_ISS(wvA, hvA, 0);
        int gb8 = 8, gi = 0;
        while (true) {
            AG1_ISS(wvB, hvB, gb8); gb8 += 8;   // prefetch (clamped, w=0 phantom)
            AG1_FMA(wvA, hvA);
            if (++gi >= ngr) break;
            AG1_ISS(wvA, hvA, gb8); gb8 += 8;
            AG1_FMA(wvB, hvB);
            if (++gi >= ngr) break;
        }
#undef AG1_ISS
#undef AG1_FMA
    }

    float sinv = 1.f / (wsum + 1e-16f);
    float4 bv = *(const float4*)(bias + s * 128 + l5 * 4);
    float o0 = elu1(a0 * sinv + bv.x);
    float o1 = elu1(a1 * sinv + bv.y);
    float o2 = elu1(a2 * sinv + bv.z);
    float o3 = elu1(a3 * sinv + bv.w);
    unsigned long long pk = (unsigned long long)f2hf(o0)
                          | ((unsigned long long)f2hf(o1) << 16)
                          | ((unsigned long long)f2hf(o2) << 32)
                          | ((unsigned long long)f2hf(o3) << 48);
    size_t o = (size_t)d * D1 + choff;
    __builtin_nontemporal_store(pk, (unsigned long long*)(outp + o));
}

// ---------------- GAT layer 2 aggregation: one wave per dst, same 2-deep pipeline ----------------

__global__ __launch_bounds__(256) void agg2_kernel(const unsigned short* __restrict__ h,
                                                   const float* __restrict__ als,
                                                   const float* __restrict__ ald,
                                                   const int* __restrict__ row_ptr,
                                                   const int* __restrict__ colidx,
                                                   const float* __restrict__ bias,
                                                   float* __restrict__ out) {
    int wave = threadIdx.x >> 6;
    int lane = threadIdx.x & 63;
    int lanesel = lane & 32;
    int l5 = lane & 31;
    int head = lanesel >> 5;
    int d = blockIdx.x * 4 + wave;
    int start = row_ptr[d], end = row_ptr[d + 1];
    int deg = end - start;
    float ald_h = ald[d * H2 + head];
    unsigned ch4 = (unsigned)(lane << 2);   // shorts within row (256-wide)

    float a0 = 0.f, a1 = 0.f, a2 = 0.f, a3 = 0.f;
    float wsum = 0.f;

    for (int c0 = 0; c0 < deg; c0 += 32) {
        int ee = start + c0 + l5;
        int idx = ee < end ? ee : end - 1;
        int sL = colidx[idx];                       // lanes l and l+32: same edge
        float ev = leaky(als[(sL << 1) + head] + ald_h);
        float wL = (ee < end) ? __expf(ev) : 0.f;   // per-head weight
        float ws = wL;
        ws += __shfl_xor(ws, 16); ws += __shfl_xor(ws, 8);
        ws += __shfl_xor(ws, 4);  ws += __shfl_xor(ws, 2);  ws += __shfl_xor(ws, 1);
        wsum += ws;

        int n = deg - c0; if (n > 32) n = 32;
        int ngr = ((n + 7) & ~7) >> 3;

        ushort4 hvA[8], hvB[8];
        float wvA[8], wvB[8];

#define AG2_ISS(WV, HV, BASE)                                                    \
        {                                                                        \
            _Pragma("unroll")                                                    \
            for (int j = 0; j < 8; j++) {                                        \
                int kk = (BASE) + j; kk = kk < 32 ? kk : 31;                     \
                int ssj = __builtin_amdgcn_readlane(sL, kk);                     \
                WV[j] = __shfl(wL, kk + lanesel);                                \
                HV[j] = *(const ushort4*)(h + (((unsigned)ssj << 8) + ch4));     \
            }                                                                    \
        }
#define AG2_FMA(WV, HV)                                                          \
        {                                                                        \
            _Pragma("unroll")                                                    \
            for (int j = 0; j < 8; j++) {                                        \
                float w = WV[j];                                                 \
                a0 += w * hf2f(HV[j].x); a1 += w * hf2f(HV[j].y);                \
                a2 += w * hf2f(HV[j].z); a3 += w * hf2f(HV[j].w);                \
            }                                                                    \
        }

        AG2_ISS(wvA, hvA, 0);
        int gb8 = 8, gi = 0;
        while (true) {
            AG2_ISS(wvB, hvB, gb8); gb8 += 8;   // prefetch (clamped, w=0 phantom)
            AG2_FMA(wvA, hvA);
            if (++gi >= ngr) break;
            AG2_ISS(wvA, hvA, gb8); gb8 += 8;
            AG2_FMA(wvB, hvB);
            if (++gi >= ngr) break;
        }
#undef AG2_ISS
#undef AG2_FMA
    }

    float sinv = 1.f / (wsum + 1e-16f);
    float r0 = a0 * sinv, r1 = a1 * sinv, r2 = a2 * sinv, r3 = a3 * sinv;
    r0 += __shfl_xor(r0, 32);
    r1 += __shfl_xor(r1, 32);
    r2 += __shfl_xor(r2, 32);
    r3 += __shfl_xor(r3, 32);
    if (lane < 32) {
        float4 bv = *(const float4*)(bias + (l5 << 2));
        float4 o;
        o.x = elu1(r0 * 0.5f + bv.x);
        o.y = elu1(r1 * 0.5f + bv.y);
        o.z = elu1(r2 * 0.5f + bv.z);
        o.w = elu1(r3 * 0.5f + bv.w);
        *(float4*)(out + (size_t)d * OUT2 + (l5 << 2)) = o;
    }
}

// ---------------- pool + final fused (256 blocks, 1 grid barrier) ----------------

__global__ __launch_bounds__(256) void poolfinal_kernel(const float* __restrict__ h2,
                                                        const int* __restrict__ batch,
                                                        float* __restrict__ pooled_sum,
                                                        const int* __restrict__ n_g_i,
                                                        const int* __restrict__ e_cnt,
                                                        const float* __restrict__ projW,
                                                        const float* __restrict__ projb,
                                                        const float* __restrict__ lng,
                                                        const float* __restrict__ lnb,
                                                        const float* __restrict__ rhW1,
                                                        const float* __restrict__ rhb1,
                                                        const float* __restrict__ rhW2,
                                                        const float* __restrict__ rhb2,
                                                        float* __restrict__ out_se,
                                                        float* __restrict__ out_risk,
                                                        int* bc, int* bg) {
    int t = threadIdx.x;
    __shared__ float4 pr[4][32];
    __shared__ float pooled[OUT2];
    __shared__ float pe[768];
    __shared__ float red[256];
    __shared__ float hid[32];
    __shared__ float stat_mu, stat_inv;

    // phase 1: pool (batch is SORTED)
    {
        int col = (t & 31) << 2;        // float4 channel offset
        int chain = t >> 5;             // 8 chains x 8 consecutive nodes
        int nbase = blockIdx.x * 64;
        int n0 = nbase + chain * 8;
        float ax = 0.f, ay = 0.f, az = 0.f, aw = 0.f;
        int gfirst = batch[nbase];
        if (gfirst == batch[nbase + 63]) {
            // pure block (common): chain sums -> shfl/LDS tree -> 128 atomics
#pragma unroll
            for (int i = 0; i < 8; i++) {
                float4 v = *(const float4*)(h2 + (size_t)(n0 + i) * OUT2 + col);
                ax += v.x; ay += v.y; az += v.z; aw += v.w;
            }
            ax += __shfl_xor(ax, 32); ay += __shfl_xor(ay, 32);
            az += __shfl_xor(az, 32); aw += __shfl_xor(aw, 32);
            int wv = t >> 6, l5 = t & 31;
            if ((t & 32) == 0) pr[wv][l5] = make_float4(ax, ay, az, aw);
            __syncthreads();
            if (t < 32) {
                float4 s0 = pr[0][t], s1 = pr[1][t], s2 = pr[2][t], s3 = pr[3][t];
                float sx = (s0.x + s1.x) + (s2.x + s3.x);
                float sy = (s0.y + s1.y) + (s2.y + s3.y);
                float sz = (s0.z + s1.z) + (s2.z + s3.z);
                float sw = (s0.w + s1.w) + (s2.w + s3.w);
                float* dst = pooled_sum + gfirst * OUT2 + (t << 2);
                atomicAdd(dst + 0, sx); atomicAdd(dst + 1, sy);
                atomicAdd(dst + 2, sz); atomicAdd(dst + 3, sw);
            }
        } else {
            // mixed block (rare): per-chain segment atomics
            int curg = batch[n0];
#pragma unroll
            for (int i = 0; i < 8; i++) {
                int g = batch[n0 + i];
                if (g != curg) {
                    float* dst = pooled_sum + curg * OUT2 + col;
                    atomicAdd(dst + 0, ax); atomicAdd(dst + 1, ay);
                    atomicAdd(dst + 2, az); atomicAdd(dst + 3, aw);
                    ax = ay = az = aw = 0.f; curg = g;
                }
                float4 v = *(const float4*)(h2 + (size_t)(n0 + i) * OUT2 + col);
                ax += v.x; ay += v.y; az += v.z; aw += v.w;
            }
            float* dst = pooled_sum + curg * OUT2 + col;
            atomicAdd(dst + 0, ax); atomicAdd(dst + 1, ay);
            atomicAdd(dst + 2, az); atomicAdd(dst + 3, aw);
        }
    }
    grid_barrier(bc, bg, 256);
    if (blockIdx.x >= NB) return;

    // phase 2: per-graph head (blocks 0..7)
    int gb = blockIdx.x;
    float ng = (float)n_g_i[gb];
    if (t < OUT2) {
        float ps = __hip_atomic_load(&pooled_sum[gb * OUT2 + t], __ATOMIC_RELAXED,
                                     __HIP_MEMORY_SCOPE_AGENT);
        pooled[t] = ps / fmaxf(ng, 1.0f);
    }
    __syncthreads();

    for (int j = t; j < 768; j += 256) {
        const float* wr = projW + (size_t)j * OUT2;
        float s = projb[j];
        for (int c = 0; c < OUT2; c++) s += pooled[c] * wr[c];
        pe[j] = s;
    }
    __syncthreads();

    float ls = 0.f, lq = 0.f;
    for (int j = t; j < 768; j += 256) { float v = pe[j]; ls += v; lq += v * v; }
    red[t] = ls;
    __syncthreads();
    for (int off = 128; off; off >>= 1) { if (t < off) red[t] += red[t + off]; __syncthreads(); }
    float tot = red[0];
    __syncthreads();
    red[t] = lq;
    __syncthreads();
    for (int off = 128; off; off >>= 1) { if (t < off) red[t] += red[t + off]; __syncthreads(); }
    float totq = red[0];
    if (t == 0) {
        float mu = tot / 768.f;
        float var = totq / 768.f - mu * mu;
        stat_mu = mu;
        stat_inv = 1.f / sqrtf(var + 1e-5f);
    }
    __syncthreads();
    float mu = stat_mu, inv = stat_inv;
    for (int j = t; j < 768; j += 256)
        out_se[(size_t)gb * 768 + j] = (pe[j] - mu) * inv * lng[j] + lnb[j];

    float s0 = (float)e_cnt[gb] / (ng + 1e-6f);
    float s1 = logf(ng + 1.0f);
    if (t < 32) {
        const float* wr = rhW1 + t * (OUT2 + 2);
        float s = rhb1[t];
        for (int c = 0; c < OUT2; c++) s += pooled[c] * wr[c];
        s += s0 * wr[OUT2] + s1 * wr[OUT2 + 1];
        hid[t] = fmaxf(s, 0.f);
    }
    __syncthreads();
    if (t == 0) {
        float s = rhb2[0];
        for (int k = 0; k < 32; k++) s += hid[k] * rhW2[k];
        out_risk[gb] = 1.f / (1.f + __expf(-s));
    }
}

// ---------------- launch ----------------

extern "C" void kernel_launch(void* const* d_in, const int* in_sizes, int n_in,
                              void* d_out, int out_size, void* d_ws, size_t ws_size,
                              hipStream_t stream) {
    const float* x     = (const float*)d_in[0];
    const int*   ei    = (const int*)  d_in[1];
    const int*   batch = (const int*)  d_in[2];
    const float* W1    = (const float*)d_in[3];
    const float* a_s1  = (const float*)d_in[4];
    const float* a_d1  = (const float*)d_in[5];
    const float* b1    = (const float*)d_in[6];
    const float* W2    = (const float*)d_in[7];
    const float* a_s2  = (const float*)d_in[8];
    const float* a_d2  = (const float*)d_in[9];
    const float* b2    = (const float*)d_in[10];
    const float* projW = (const float*)d_in[11];
    const float* projb = (const float*)d_in[12];
    const float* lng   = (const float*)d_in[13];
    const float* lnb   = (const float*)d_in[14];
    const float* rhW1  = (const float*)d_in[15];
    const float* rhb1  = (const float*)d_in[16];
    const float* rhW2  = (const float*)d_in[17];
    const float* rhb2  = (const float*)d_in[18];

    char* ws = (char*)d_ws;
    size_t off = 0;
    auto alloc = [&](size_t bytes) -> void* {
        void* p = ws + off;
        off += (bytes + 255) & ~(size_t)255;
        return p;
    };

    // regionA: x_f (25 MB) during gemm1, then h1a (33.5 MB) = agg1 out / gemm2 A
    unsigned short* regionA = (unsigned short*)alloc((size_t)NN * D1 * 2);
    unsigned short* x_f  = regionA;
    unsigned short* h1a  = regionA;

    unsigned short* h1f  = (unsigned short*)alloc((size_t)NN * D1 * 2);   // gemm1 out (fp16)
    unsigned short* h2ft = (unsigned short*)alloc((size_t)NN * D2 * 2);   // gemm2 out (fp16)
    unsigned short* W1f  = (unsigned short*)alloc((size_t)D1 * IN_F * 2);
    unsigned short* W2f  = (unsigned short*)alloc((size_t)D2 * D1 * 2);
    float* als1   = (float*)alloc((size_t)NN * H1 * 4);
    float* ald1   = (float*)alloc((size_t)NN * H1 * 4);
    float* als2   = (float*)alloc((size_t)NN * H2 * 4);
    float* ald2   = (float*)alloc((size_t)NN * H2 * 4);
    int*   row_ptr= (int*)  alloc((size_t)(NN + 1) * 4);
    int*   colidx = (int*)  alloc((size_t)ET * 4);
    size_t zoff = off;
    int*   deg    = (int*)  alloc((size_t)NN * 4);
    int*   cursor = (int*)  alloc((size_t)NN * 4);
    int*   n_g    = (int*)  alloc((size_t)NB * 4);
    int*   e_cnt  = (int*)  alloc((size_t)NB * 4);
    float* pooled = (float*)alloc((size_t)NB * OUT2 * 4);
    int*   bars   = (int*)  alloc((size_t)8 * 4);   // [0]=pf cnt [1]=pf gen
    size_t zbytes = off - zoff;

    float* out_se   = (float*)d_out;
    float* h2out    = out_se + NB * 768;
    float* out_risk = h2out + (size_t)NN * OUT2;

    // k1: conversions + zero-fill (memset dispatch eliminated)
    {
        int ntot = NN * IN_F / 4 + D1 * IN_F / 4 + D2 * D1 / 4;
        int zunits = (int)(zbytes / 16);
        int grid = (ntot + zunits + 255) / 256;
        prep_kernel<<<grid, 256, 0, stream>>>(x, x_f, W1, W1f, W2, W2f,
                                              (float4*)(ws + zoff), zunits);
    }

    // k2/k3: CSR hist + scan
    hist_kernel<<<(EE + 255) / 256, 256, 0, stream>>>(ei, batch, deg, n_g, e_cnt);
    scan_kernel<<<1, 1024, 0, stream>>>(deg, row_ptr);

    // k4: gemm1 + scatter trailing blocks (scatter hides under the GEMM)
    {
        int gb = (NN / BM) * (D1 / BN);              // 1024
        int sb = (ET + 255) / 256;                   // 1088
        gemm_mfma<<<gb + sb, 256, 0, stream>>>(x_f, W1f, h1f, NN, D1, IN_F,
                                               gb, ei, row_ptr, cursor, colidx);
    }

    al1_kernel<<<NN, 256, 0, stream>>>(h1f, a_s1, a_d1, als1, ald1);
    agg1_kernel<<<NN, 256, 0, stream>>>(h1f, als1, ald1, row_ptr, colidx, b1, h1a);

    {
        int gb = (NN / BM) * (D2 / BN);              // 256, no scatter blocks
        gemm_mfma<<<gb, 256, 0, stream>>>(h1a, W2f, h2ft, NN, D2, D1,
                                          gb, ei, row_ptr, cursor, colidx);
    }
    al2_kernel<<<NN / 2, 256, 0, stream>>>(h2ft, a_s2, a_d2, als2, ald2);
    agg2_kernel<<<NN / 4, 256, 0, stream>>>(h2ft, als2, ald2, row_ptr, colidx, b2, h2out);

    // k9: pool + final fused (256 blocks)
    poolfinal_kernel<<<NN / 64, 256, 0, stream>>>(h2out, batch, pooled, n_g, e_cnt,
                                                  projW, projb, lng, lnb,
                                                  rhW1, rhb1, rhW2, rhb2,
                                                  out_se, out_risk, &bars[0], &bars[1]);
}

// Round 15
// 358.525 us; speedup vs baseline: 1.0807x; 1.0807x over previous
//
#include <hip/hip_runtime.h>
#include <math.h>

#define NN    16384
#define EE    262144
#define ET    (EE + NN)      // edges + self loops
#define NB    8
#define IN_F  768
#define HID1  256
#define H1    4
#define D1    (H1*HID1)      // 1024
#define OUT2  128
#define H2    2
#define D2    (H2*OUT2)      // 256

typedef __attribute__((ext_vector_type(8))) _Float16 f16x8;
typedef __attribute__((ext_vector_type(4))) float f32x4;

__device__ __forceinline__ float hf2f(unsigned short u) {
    union { unsigned short u; _Float16 h; } c; c.u = u; return (float)c.h;
}
__device__ __forceinline__ unsigned short f2hf(float f) {
    union { unsigned short u; _Float16 h; } c; c.h = (_Float16)f; return c.u;
}

// ---------------- prep: fp32->fp16 conversions + workspace zero-fill ----------------

__global__ void prep_kernel(const float* __restrict__ x,  unsigned short* __restrict__ xo,
                            const float* __restrict__ w1, unsigned short* __restrict__ w1o,
                            const float* __restrict__ w2, unsigned short* __restrict__ w2o,
                            float4* __restrict__ zbase, int zunits) {
    const int n1 = NN * IN_F / 4;
    const int n2 = D1 * IN_F / 4;
    const int n3 = D2 * D1 / 4;
    int i = blockIdx.x * blockDim.x + threadIdx.x;
    if (i < n1 + n2 + n3) {
        const float* src; unsigned short* dst; int j;
        if (i < n1)           { src = x;  dst = xo;  j = i; }
        else if (i < n1 + n2) { src = w1; dst = w1o; j = i - n1; }
        else                  { src = w2; dst = w2o; j = i - n1 - n2; }
        float4 v = ((const float4*)src)[j];
        ushort4 h;
        h.x = f2hf(v.x); h.y = f2hf(v.y); h.z = f2hf(v.z); h.w = f2hf(v.w);
        ((ushort4*)dst)[j] = h;
    } else {
        int j = i - (n1 + n2 + n3);
        if (j < zunits) zbase[j] = make_float4(0.f, 0.f, 0.f, 0.f);
    }
}

// ---------------- CSR build (proven r10 versions) ----------------

__global__ void hist_kernel(const int* __restrict__ ei, const int* __restrict__ batch,
                            int* __restrict__ deg, int* __restrict__ n_g, int* __restrict__ e_cnt) {
    __shared__ int le[NB], ln[NB];
    int tid = threadIdx.x;
    if (tid < NB) { le[tid] = 0; ln[tid] = 0; }
    __syncthreads();
    int t = blockIdx.x * blockDim.x + tid;
    if (t < EE) {
        int s = ei[t];
        int d = ei[EE + t];
        atomicAdd(&deg[d], 1);
        atomicAdd(&le[batch[s]], 1);
    }
    if (t < NN) {
        atomicAdd(&ln[batch[t]], 1);
    }
    __syncthreads();
    if (tid < NB) {
        if (le[tid]) atomicAdd(&e_cnt[tid], le[tid]);
        if (ln[tid]) atomicAdd(&n_g[tid], ln[tid]);
    }
}

__global__ __launch_bounds__(1024) void scan_kernel(const int* __restrict__ deg, int* __restrict__ row_ptr) {
    __shared__ int sums[1024];
    int t = threadIdx.x;
    int base = t * 16;
    int local[16];
    int acc = 0;
#pragma unroll
    for (int i = 0; i < 16; i++) { local[i] = acc; acc += deg[base + i] + 1; }  // +1 = self loop
    sums[t] = acc;
    __syncthreads();
    for (int off = 1; off < 1024; off <<= 1) {
        int v = (t >= off) ? sums[t - off] : 0;
        __syncthreads();
        sums[t] += v;
        __syncthreads();
    }
    int prev = (t == 0) ? 0 : sums[t - 1];
#pragma unroll
    for (int i = 0; i < 16; i++) row_ptr[base + i] = prev + local[i];
    if (t == 1023) row_ptr[NN] = sums[1023];
}

// ---------------- fp16 MFMA GEMM (+ optional scatter trailing blocks) ----------------

__device__ __forceinline__ void ld_lds16(const unsigned short* g, unsigned short* l) {
    __builtin_amdgcn_global_load_lds((__attribute__((address_space(1))) void*)g,
                                     (__attribute__((address_space(3))) void*)l, 16, 0, 0);
}

#define BM 128
#define BN 128
#define BK 32

__global__ __launch_bounds__(256) void gemm_mfma(const unsigned short* __restrict__ A,
                                                 const unsigned short* __restrict__ B,
                                                 unsigned short* __restrict__ C,
                                                 int M, int N, int K,
                                                 int gemmBlocks,
                                                 const int* __restrict__ ei,
                                                 const int* __restrict__ row_ptr,
                                                 int* __restrict__ cursor,
                                                 int* __restrict__ colidx) {
    if ((int)blockIdx.x >= gemmBlocks) {
        int t = (blockIdx.x - gemmBlocks) * 256 + threadIdx.x;
        if (t < ET) {
            int s, d;
            if (t < EE) { s = ei[t]; d = ei[EE + t]; }
            else        { s = d = t - EE; }
            int pos = row_ptr[d] + atomicAdd(&cursor[d], 1);
            colidx[pos] = s;
        }
        return;
    }

    __shared__ __align__(16) unsigned short sA[BM * BK];
    __shared__ __align__(16) unsigned short sB[BN * BK];
    int t = threadIdx.x;
    int lane = t & 63, wave = t >> 6;

    // XCD swizzle: row-stripe r = (b/8/NC)*8 + b%8, col c = (b/8)%NC
    int NC = N / BN;
    int b = blockIdx.x;
    int xcd = b & 7;
    int idx = b >> 3;
    int c = idx % NC;
    int rg = idx / NC;
    int bm = (rg * 8 + xcd) * BM;
    int bn = c * BN;

    int wm = (wave & 1) * 64, wn = (wave >> 1) * 64;

    // staging: wave0/1 -> A rows 0-63 / 64-127; wave2/3 -> B halves
    const unsigned short* gbase;
    unsigned short* lbase;
    {
        int hrow = (wave & 1) * 64;
        if (wave < 2) { gbase = A + (size_t)(bm + hrow) * K; lbase = sA + hrow * BK; }
        else          { gbase = B + (size_t)(bn + hrow) * K; lbase = sB + hrow * BK; }
    }
    int schunk = (lane & 3) ^ ((lane >> 3) & 3);
    const unsigned short* gsrc = gbase + (size_t)(lane >> 2) * K + schunk * 8;

    f32x4 zero = {0.f, 0.f, 0.f, 0.f};
    f32x4 acc[4][4];
#pragma unroll
    for (int i = 0; i < 4; i++)
#pragma unroll
        for (int j = 0; j < 4; j++) acc[i][j] = zero;

    int row16 = lane & 15;
    int kq = ((lane >> 4) ^ ((row16 >> 1) & 3)) * 8;

    for (int k0 = 0; k0 < K; k0 += BK) {
#pragma unroll
        for (int i = 0; i < 4; i++)
            ld_lds16(gsrc + k0 + (size_t)(i * 16) * K, lbase + i * 16 * BK);
        __syncthreads();

        f16x8 ah[4], bh[4];
#pragma unroll
        for (int mt = 0; mt < 4; mt++)
            ah[mt] = *(const f16x8*)&sA[(wm + mt * 16 + row16) * BK + kq];
#pragma unroll
        for (int nt = 0; nt < 4; nt++)
            bh[nt] = *(const f16x8*)&sB[(wn + nt * 16 + row16) * BK + kq];
#pragma unroll
        for (int mt = 0; mt < 4; mt++)
#pragma unroll
            for (int nt = 0; nt < 4; nt++)
                acc[mt][nt] = __builtin_amdgcn_mfma_f32_16x16x32_f16(ah[mt], bh[nt], acc[mt][nt], 0, 0, 0);
        __syncthreads();
    }

    int crow0 = bm + wm + (lane >> 4) * 4;
    int ccol0 = bn + wn + row16;
#pragma unroll
    for (int mt = 0; mt < 4; mt++)
#pragma unroll
        for (int nt = 0; nt < 4; nt++)
#pragma unroll
            for (int reg = 0; reg < 4; reg++)
                C[(size_t)(crow0 + mt * 16 + reg) * N + ccol0 + nt * 16] = f2hf(acc[mt][nt][reg]);
}

// ---------------- attention logits: one wave per (node, head), vector loads ----------------

__global__ __launch_bounds__(256) void al1_kernel(const unsigned short* __restrict__ h,
                                                  const float* __restrict__ a_s,
                                                  const float* __restrict__ a_d,
                                                  float* __restrict__ als,
                                                  float* __restrict__ ald) {
    int node = blockIdx.x;
    int head = threadIdx.x >> 6;
    int lane = threadIdx.x & 63;
    int co = head * HID1 + lane * 4;
    ushort4 hv = *(const ushort4*)(h + (size_t)node * D1 + co);
    float4 as = *(const float4*)(a_s + co);
    float4 ad = *(const float4*)(a_d + co);
    float h0 = hf2f(hv.x), h1 = hf2f(hv.y), h2 = hf2f(hv.z), h3 = hf2f(hv.w);
    float ss = h0 * as.x + h1 * as.y + h2 * as.z + h3 * as.w;
    float sd = h0 * ad.x + h1 * ad.y + h2 * ad.z + h3 * ad.w;
#pragma unroll
    for (int off = 32; off; off >>= 1) {
        ss += __shfl_down(ss, off);
        sd += __shfl_down(sd, off);
    }
    if (lane == 0) {
        als[node * H1 + head] = ss;
        ald[node * H1 + head] = sd;
    }
}

__global__ __launch_bounds__(256) void al2_kernel(const unsigned short* __restrict__ h,
                                                  const float* __restrict__ a_s,
                                                  const float* __restrict__ a_d,
                                                  float* __restrict__ als,
                                                  float* __restrict__ ald) {
    int unit = threadIdx.x >> 6;            // 4 units: 2 nodes x 2 heads
    int node = blockIdx.x * 2 + (unit >> 1);
    int head = unit & 1;
    int lane = threadIdx.x & 63;
    int co = head * OUT2 + lane * 2;
    ushort2 hv = *(const ushort2*)(h + (size_t)node * D2 + co);
    float2 as = *(const float2*)(a_s + co);
    float2 ad = *(const float2*)(a_d + co);
    float h0 = hf2f(hv.x), h1 = hf2f(hv.y);
    float ss = h0 * as.x + h1 * as.y;
    float sd = h0 * ad.x + h1 * ad.y;
#pragma unroll
    for (int off = 32; off; off >>= 1) {
        ss += __shfl_down(ss, off);
        sd += __shfl_down(sd, off);
    }
    if (lane == 0) {
        als[node * H2 + head] = ss;
        ald[node * H2 + head] = sd;
    }
}

__device__ __forceinline__ float leaky(float v) { return v > 0.f ? v : 0.2f * v; }
__device__ __forceinline__ float elu1(float v) { return v > 0.f ? v : (__expf(v) - 1.f); }

// ---------------- GAT layer 1 aggregation: channel-sliced + 2-dst half-waves ----------------
// r13 version (no gather pipeline: r14's 2-deep variant raised VGPR 36->60,
// halved occupancy 63->36%, and cost +11 us -- TLP was doing the latency hiding).

__global__ __launch_bounds__(256) void agg1_kernel(const unsigned short* __restrict__ h,
                                                   const float* __restrict__ als,
                                                   const float* __restrict__ ald,
                                                   const int* __restrict__ row_ptr,
                                                   const int* __restrict__ colidx,
                                                   const float* __restrict__ bias,
                                                   unsigned short* __restrict__ outp) {
    int b = blockIdx.x;
    int s = b & 7;             // slice -> XCD s
    int g = b >> 3;            // group of 8 dsts
    int wave = threadIdx.x >> 6;
    int lane = threadIdx.x & 63;
    int lanesel = lane & 32;   // half select
    int l5 = lane & 31;
    int d = g * 8 + wave * 2 + (lanesel >> 5);
    int head = s >> 1;
    int start = row_ptr[d], end = row_ptr[d + 1];
    int deg = end - start;
    int degO = __shfl_xor(deg, 32);
    int degmax = max(deg, degO);
    float ald_h = ald[d * H1 + head];
    unsigned choff = (unsigned)(s * 128 + l5 * 4);   // shorts within row

    float a0 = 0.f, a1 = 0.f, a2 = 0.f, a3 = 0.f;
    float wsum = 0.f;

    for (int c0 = 0; c0 < degmax; c0 += 32) {
        int ee = start + c0 + l5;
        int idx = ee < end ? ee : end - 1;
        int sL = colidx[idx];
        float ev = leaky(als[(sL << 2) + head] + ald_h);
        float wL = (ee < end) ? __expf(ev) : 0.f;
        float ws = wL;
        ws += __shfl_xor(ws, 16); ws += __shfl_xor(ws, 8);
        ws += __shfl_xor(ws, 4);  ws += __shfl_xor(ws, 2);  ws += __shfl_xor(ws, 1);
        wsum += ws;

        int n = degmax - c0; if (n > 32) n = 32;
        int n8 = (n + 7) & ~7;
        for (int k = 0; k < n8; k += 8) {
            ushort4 hv[8]; float wv[8];
#pragma unroll
            for (int j = 0; j < 8; j++) {
                int src = k + j + lanesel;          // own half's edge slot
                int ssj = __shfl(sL, src);
                wv[j]   = __shfl(wL, src);
                hv[j] = *(const ushort4*)(h + (((unsigned)ssj << 10) + choff));
            }
#pragma unroll
            for (int j = 0; j < 8; j++) {
                float w = wv[j];
                a0 += w * hf2f(hv[j].x); a1 += w * hf2f(hv[j].y);
                a2 += w * hf2f(hv[j].z); a3 += w * hf2f(hv[j].w);
            }
        }
    }

    float sinv = 1.f / (wsum + 1e-16f);
    float4 bv = *(const float4*)(bias + s * 128 + l5 * 4);
    float o0 = elu1(a0 * sinv + bv.x);
    float o1 = elu1(a1 * sinv + bv.y);
    float o2 = elu1(a2 * sinv + bv.z);
    float o3 = elu1(a3 * sinv + bv.w);
    unsigned long long pk = (unsigned long long)f2hf(o0)
                          | ((unsigned long long)f2hf(o1) << 16)
                          | ((unsigned long long)f2hf(o2) << 32)
                          | ((unsigned long long)f2hf(o3) << 48);
    size_t o = (size_t)d * D1 + choff;
    __builtin_nontemporal_store(pk, (unsigned long long*)(outp + o));
}

// ---------------- GAT layer 2 aggregation: one wave per dst, ushort4 loads ----------------

__global__ __launch_bounds__(256) void agg2_kernel(const unsigned short* __restrict__ h,
                                                   const float* __restrict__ als,
                                                   const float* __restrict__ ald,
                                                   const int* __restrict__ row_ptr,
                                                   const int* __restrict__ colidx,
                                                   const float* __restrict__ bias,
                                                   float* __restrict__ out) {
    int wave = threadIdx.x >> 6;
    int lane = threadIdx.x & 63;
    int lanesel = lane & 32;
    int l5 = lane & 31;
    int head = lanesel >> 5;
    int d = blockIdx.x * 4 + wave;
    int start = row_ptr[d], end = row_ptr[d + 1];
    int deg = end - start;
    float ald_h = ald[d * H2 + head];
    unsigned ch4 = (unsigned)(lane << 2);   // shorts within row (256-wide)

    float a0 = 0.f, a1 = 0.f, a2 = 0.f, a3 = 0.f;
    float wsum = 0.f;

    for (int c0 = 0; c0 < deg; c0 += 32) {
        int ee = start + c0 + l5;
        int idx = ee < end ? ee : end - 1;
        int sL = colidx[idx];                       // lanes l and l+32: same edge
        float ev = leaky(als[(sL << 1) + head] + ald_h);
        float wL = (ee < end) ? __expf(ev) : 0.f;   // per-head weight
        float ws = wL;
        ws += __shfl_xor(ws, 16); ws += __shfl_xor(ws, 8);
        ws += __shfl_xor(ws, 4);  ws += __shfl_xor(ws, 2);  ws += __shfl_xor(ws, 1);
        wsum += ws;

        int n = deg - c0; if (n > 32) n = 32;
        int n8 = (n + 7) & ~7;
        for (int k = 0; k < n8; k += 8) {
            ushort4 hv[8]; float wv[8];
#pragma unroll
            for (int j = 0; j < 8; j++) {
                int ssj = __builtin_amdgcn_readlane(sL, k + j);
                wv[j] = __shfl(wL, k + j + lanesel);
                hv[j] = *(const ushort4*)(h + (((unsigned)ssj << 8) + ch4));
            }
#pragma unroll
            for (int j = 0; j < 8; j++) {
                float w = wv[j];
                a0 += w * hf2f(hv[j].x); a1 += w * hf2f(hv[j].y);
                a2 += w * hf2f(hv[j].z); a3 += w * hf2f(hv[j].w);
            }
        }
    }

    float sinv = 1.f / (wsum + 1e-16f);
    float r0 = a0 * sinv, r1 = a1 * sinv, r2 = a2 * sinv, r3 = a3 * sinv;
    r0 += __shfl_xor(r0, 32);
    r1 += __shfl_xor(r1, 32);
    r2 += __shfl_xor(r2, 32);
    r3 += __shfl_xor(r3, 32);
    if (lane < 32) {
        float4 bv = *(const float4*)(bias + (l5 << 2));
        float4 o;
        o.x = elu1(r0 * 0.5f + bv.x);
        o.y = elu1(r1 * 0.5f + bv.y);
        o.z = elu1(r2 * 0.5f + bv.z);
        o.w = elu1(r3 * 0.5f + bv.w);
        *(float4*)(out + (size_t)d * OUT2 + (l5 << 2)) = o;
    }
}

// ---------------- pooling (256 blocks, vectorized; NO grid barrier) ----------------
// r13's fused poolfinal spent ~26 us in the 256-block AGENT-scope spin barrier
// (calibrated from r11's histscan: 3 barriers ~ 79 us). A kernel boundary is
// ~3-5 us. Split back into pool + final.

__global__ __launch_bounds__(256) void pool_kernel(const float* __restrict__ h2,
                                                   const int* __restrict__ batch,
                                                   float* __restrict__ pooled_sum) {
    int t = threadIdx.x;
    __shared__ float4 pr[4][32];
    int col = (t & 31) << 2;        // float4 channel offset
    int chain = t >> 5;             // 8 chains x 8 consecutive nodes
    int nbase = blockIdx.x * 64;
    int n0 = nbase + chain * 8;
    float ax = 0.f, ay = 0.f, az = 0.f, aw = 0.f;
    int gfirst = batch[nbase];
    if (gfirst == batch[nbase + 63]) {
        // pure block (common): chain sums -> shfl/LDS tree -> 128 atomics
#pragma unroll
        for (int i = 0; i < 8; i++) {
            float4 v = *(const float4*)(h2 + (size_t)(n0 + i) * OUT2 + col);
            ax += v.x; ay += v.y; az += v.z; aw += v.w;
        }
        ax += __shfl_xor(ax, 32); ay += __shfl_xor(ay, 32);
        az += __shfl_xor(az, 32); aw += __shfl_xor(aw, 32);
        int wv = t >> 6, l5 = t & 31;
        if ((t & 32) == 0) pr[wv][l5] = make_float4(ax, ay, az, aw);
        __syncthreads();
        if (t < 32) {
            float4 s0 = pr[0][t], s1 = pr[1][t], s2 = pr[2][t], s3 = pr[3][t];
            float sx = (s0.x + s1.x) + (s2.x + s3.x);
            float sy = (s0.y + s1.y) + (s2.y + s3.y);
            float sz = (s0.z + s1.z) + (s2.z + s3.z);
            float sw = (s0.w + s1.w) + (s2.w + s3.w);
            float* dst = pooled_sum + gfirst * OUT2 + (t << 2);
            atomicAdd(dst + 0, sx); atomicAdd(dst + 1, sy);
            atomicAdd(dst + 2, sz); atomicAdd(dst + 3, sw);
        }
    } else {
        // mixed block (rare): per-chain segment atomics
        int curg = batch[n0];
#pragma unroll
        for (int i = 0; i < 8; i++) {
            int g = batch[n0 + i];
            if (g != curg) {
                float* dst = pooled_sum + curg * OUT2 + col;
                atomicAdd(dst + 0, ax); atomicAdd(dst + 1, ay);
                atomicAdd(dst + 2, az); atomicAdd(dst + 3, aw);
                ax = ay = az = aw = 0.f; curg = g;
            }
            float4 v = *(const float4*)(h2 + (size_t)(n0 + i) * OUT2 + col);
            ax += v.x; ay += v.y; az += v.z; aw += v.w;
        }
        float* dst = pooled_sum + curg * OUT2 + col;
        atomicAdd(dst + 0, ax); atomicAdd(dst + 1, ay);
        atomicAdd(dst + 2, az); atomicAdd(dst + 3, aw);
    }
}

// ---------------- per-graph head: proj + LN + risk MLP ----------------

__global__ __launch_bounds__(256) void final_kernel(const float* __restrict__ pooled_sum,
                                                    const int* __restrict__ n_g_i,
                                                    const int* __restrict__ e_cnt,
                                                    const float* __restrict__ projW,
                                                    const float* __restrict__ projb,
                                                    const float* __restrict__ lng,
                                                    const float* __restrict__ lnb,
                                                    const float* __restrict__ rhW1,
                                                    const float* __restrict__ rhb1,
                                                    const float* __restrict__ rhW2,
                                                    const float* __restrict__ rhb2,
                                                    float* __restrict__ out_se,
                                                    float* __restrict__ out_risk) {
    int b = blockIdx.x;
    int t = threadIdx.x;
    __shared__ float pooled[OUT2];
    __shared__ float pe[768];
    __shared__ float red[256];
    __shared__ float hid[32];
    __shared__ float stat_mu, stat_inv;

    float ng = (float)n_g_i[b];
    if (t < OUT2) pooled[t] = pooled_sum[b * OUT2 + t] / fmaxf(ng, 1.0f);
    __syncthreads();

    for (int j = t; j < 768; j += 256) {
        const float* wr = projW + (size_t)j * OUT2;
        float s = projb[j];
        for (int c = 0; c < OUT2; c++) s += pooled[c] * wr[c];
        pe[j] = s;
    }
    __syncthreads();

    float ls = 0.f, lq = 0.f;
    for (int j = t; j < 768; j += 256) { float v = pe[j]; ls += v; lq += v * v; }
    red[t] = ls;
    __syncthreads();
    for (int off = 128; off; off >>= 1) { if (t < off) red[t] += red[t + off]; __syncthreads(); }
    float tot = red[0];
    __syncthreads();
    red[t] = lq;
    __syncthreads();
    for (int off = 128; off; off >>= 1) { if (t < off) red[t] += red[t + off]; __syncthreads(); }
    float totq = red[0];
    if (t == 0) {
        float mu = tot / 768.f;
        float var = totq / 768.f - mu * mu;
        stat_mu = mu;
        stat_inv = 1.f / sqrtf(var + 1e-5f);
    }
    __syncthreads();
    float mu = stat_mu, inv = stat_inv;
    for (int j = t; j < 768; j += 256)
        out_se[(size_t)b * 768 + j] = (pe[j] - mu) * inv * lng[j] + lnb[j];

    float s0 = (float)e_cnt[b] / (ng + 1e-6f);
    float s1 = logf(ng + 1.0f);
    if (t < 32) {
        const float* wr = rhW1 + t * (OUT2 + 2);
        float s = rhb1[t];
        for (int c = 0; c < OUT2; c++) s += pooled[c] * wr[c];
        s += s0 * wr[OUT2] + s1 * wr[OUT2 + 1];
        hid[t] = fmaxf(s, 0.f);
    }
    __syncthreads();
    if (t == 0) {
        float s = rhb2[0];
        for (int k = 0; k < 32; k++) s += hid[k] * rhW2[k];
        out_risk[b] = 1.f / (1.f + __expf(-s));
    }
}

// ---------------- launch ----------------

extern "C" void kernel_launch(void* const* d_in, const int* in_sizes, int n_in,
                              void* d_out, int out_size, void* d_ws, size_t ws_size,
                              hipStream_t stream) {
    const float* x     = (const float*)d_in[0];
    const int*   ei    = (const int*)  d_in[1];
    const int*   batch = (const int*)  d_in[2];
    const float* W1    = (const float*)d_in[3];
    const float* a_s1  = (const float*)d_in[4];
    const float* a_d1  = (const float*)d_in[5];
    const float* b1    = (const float*)d_in[6];
    const float* W2    = (const float*)d_in[7];
    const float* a_s2  = (const float*)d_in[8];
    const float* a_d2  = (const float*)d_in[9];
    const float* b2    = (const float*)d_in[10];
    const float* projW = (const float*)d_in[11];
    const float* projb = (const float*)d_in[12];
    const float* lng   = (const float*)d_in[13];
    const float* lnb   = (const float*)d_in[14];
    const float* rhW1  = (const float*)d_in[15];
    const float* rhb1  = (const float*)d_in[16];
    const float* rhW2  = (const float*)d_in[17];
    const float* rhb2  = (const float*)d_in[18];

    char* ws = (char*)d_ws;
    size_t off = 0;
    auto alloc = [&](size_t bytes) -> void* {
        void* p = ws + off;
        off += (bytes + 255) & ~(size_t)255;
        return p;
    };

    // regionA: x_f (25 MB) during gemm1, then h1a (33.5 MB) = agg1 out / gemm2 A
    unsigned short* regionA = (unsigned short*)alloc((size_t)NN * D1 * 2);
    unsigned short* x_f  = regionA;
    unsigned short* h1a  = regionA;

    unsigned short* h1f  = (unsigned short*)alloc((size_t)NN * D1 * 2);   // gemm1 out (fp16)
    unsigned short* h2ft = (unsigned short*)alloc((size_t)NN * D2 * 2);   // gemm2 out (fp16)
    unsigned short* W1f  = (unsigned short*)alloc((size_t)D1 * IN_F * 2);
    unsigned short* W2f  = (unsigned short*)alloc((size_t)D2 * D1 * 2);
    float* als1   = (float*)alloc((size_t)NN * H1 * 4);
    float* ald1   = (float*)alloc((size_t)NN * H1 * 4);
    float* als2   = (float*)alloc((size_t)NN * H2 * 4);
    float* ald2   = (float*)alloc((size_t)NN * H2 * 4);
    int*   row_ptr= (int*)  alloc((size_t)(NN + 1) * 4);
    int*   colidx = (int*)  alloc((size_t)ET * 4);
    size_t zoff = off;
    int*   deg    = (int*)  alloc((size_t)NN * 4);
    int*   cursor = (int*)  alloc((size_t)NN * 4);
    int*   n_g    = (int*)  alloc((size_t)NB * 4);
    int*   e_cnt  = (int*)  alloc((size_t)NB * 4);
    float* pooled = (float*)alloc((size_t)NB * OUT2 * 4);
    size_t zbytes = off - zoff;

    float* out_se   = (float*)d_out;
    float* h2out    = out_se + NB * 768;
    float* out_risk = h2out + (size_t)NN * OUT2;

    // k1: conversions + zero-fill (memset dispatch eliminated)
    {
        int ntot = NN * IN_F / 4 + D1 * IN_F / 4 + D2 * D1 / 4;
        int zunits = (int)(zbytes / 16);
        int grid = (ntot + zunits + 255) / 256;
        prep_kernel<<<grid, 256, 0, stream>>>(x, x_f, W1, W1f, W2, W2f,
                                              (float4*)(ws + zoff), zunits);
    }

    // k2/k3: CSR hist + scan
    hist_kernel<<<(EE + 255) / 256, 256, 0, stream>>>(ei, batch, deg, n_g, e_cnt);
    scan_kernel<<<1, 1024, 0, stream>>>(deg, row_ptr);

    // k4: gemm1 + scatter trailing blocks (scatter hides under the GEMM)
    {
        int gb = (NN / BM) * (D1 / BN);              // 1024
        int sb = (ET + 255) / 256;                   // 1088
        gemm_mfma<<<gb + sb, 256, 0, stream>>>(x_f, W1f, h1f, NN, D1, IN_F,
                                               gb, ei, row_ptr, cursor, colidx);
    }

    al1_kernel<<<NN, 256, 0, stream>>>(h1f, a_s1, a_d1, als1, ald1);
    agg1_kernel<<<NN, 256, 0, stream>>>(h1f, als1, ald1, row_ptr, colidx, b1, h1a);

    {
        int gb = (NN / BM) * (D2 / BN);              // 256, no scatter blocks
        gemm_mfma<<<gb, 256, 0, stream>>>(h1a, W2f, h2ft, NN, D2, D1,
                                          gb, ei, row_ptr, cursor, colidx);
    }
    al2_kernel<<<NN / 2, 256, 0, stream>>>(h2ft, a_s2, a_d2, als2, ald2);
    agg2_kernel<<<NN / 4, 256, 0, stream>>>(h2ft, als2, ald2, row_ptr, colidx, b2, h2out);

    // k9/k10: pool (vectorized, no barrier) + final
    pool_kernel<<<NN / 64, 256, 0, stream>>>(h2out, batch, pooled);
    final_kernel<<<NB, 256, 0, stream>>>(pooled, n_g, e_cnt, projW, projb, lng, lnb,
                                         rhW1, rhb1, rhW2, rhb2, out_se, out_risk);
}